// Round 1
// baseline (1403.209 us; speedup 1.0000x reference)
//
#include <hip/hip_runtime.h>

// Shapes fixed by setup_inputs()
#define BATCH 16
#define CHAN 192
#define HW 50176            // 224*224
#define NSEG 196
#define CHALF 96            // channels per block (2 halves -> 76.8 KB LDS, 2 blocks/CU)
#define PAD 97              // LDS row stride in floats; 97%32==1 -> bank=(seg+c)%32, distinct segs never collide
#define PIXCHUNK 3136       // HW/16 pixels per block
#define NGROUP 49           // PIXCHUNK/64 groups of 64 pixels
#define CPW 6               // channels per wave (96 / 16 waves)
#define CNT_ROW (NSEG * PAD)
#define LDS_FLOATS (NSEG * PAD + NSEG)   // 19208 floats = 76,832 B

// Direct LDS scatter-add segment-sum. Grid (16 pix-chunks, 2 chan-halves, BATCH), block 1024 (16 waves).
// Whole per-(batch, chan-half) accumulator lives in LDS; hot loop has ZERO barriers.
// Wave w owns channels [cbase + w*6, +6); per 64-pixel group: 1 coalesced seg load +
// 6 coalesced 256B feature loads + 6 ds_add_f32. Counts fused (wave 0 of half 0).
__global__ __launch_bounds__(1024, 8) void accum_scatter(
        const float* __restrict__ feat,
        const int*   __restrict__ seg,
        float*       __restrict__ out,
        float*       __restrict__ cnt) {
    __shared__ float lds[LDS_FLOATS];

    const int tid   = threadIdx.x;
    const int wave  = tid >> 6;
    const int lane  = tid & 63;
    const int b     = blockIdx.z;
    const int cbase = blockIdx.y * CHALF;
    const int pstart = blockIdx.x * PIXCHUNK;
    const int lc0   = wave * CPW;

    for (int i = tid; i < LDS_FLOATS; i += 1024) lds[i] = 0.0f;
    __syncthreads();

    const int*   sp  = seg  + (size_t)b * HW + pstart + lane;
    const float* fp0 = feat + ((size_t)b * CHAN + cbase + lc0) * HW + pstart + lane;
    const bool docount = (blockIdx.y == 0) && (wave == 0);

    // one-group software pipeline: load group g+1 while ds_add'ing group g
    int   s_cur = sp[0];
    float v_cur[CPW];
#pragma unroll
    for (int j = 0; j < CPW; ++j) v_cur[j] = fp0[(size_t)j * HW];

    for (int g = 0; g < NGROUP; ++g) {
        int   s_nxt = 0;
        float v_nxt[CPW];
        if (g + 1 < NGROUP) {
            const int poff = (g + 1) * 64;
            s_nxt = sp[poff];
            const float* fp = fp0 + poff;
#pragma unroll
            for (int j = 0; j < CPW; ++j) v_nxt[j] = fp[(size_t)j * HW];
        }

        if (docount) atomicAdd(lds + CNT_ROW + s_cur, 1.0f);
        float* lrow = lds + s_cur * PAD + lc0;
#pragma unroll
        for (int j = 0; j < CPW; ++j) atomicAdd(lrow + j, v_cur[j]);

        s_cur = s_nxt;
#pragma unroll
        for (int j = 0; j < CPW; ++j) v_cur[j] = v_nxt[j];
    }
    __syncthreads();

    // flush: coalesced over channels (consecutive tid -> consecutive c)
    float* obase = out + ((size_t)b * NSEG) * CHAN + cbase;
    for (int i = tid; i < NSEG * CHALF; i += 1024) {
        const int s  = i / CHALF;
        const int lc = i - s * CHALF;
        atomicAdd(obase + (size_t)s * CHAN + lc, lds[s * PAD + lc]);
    }
    if (blockIdx.y == 0 && tid < NSEG)
        atomicAdd(cnt + b * NSEG + tid, lds[CNT_ROW + tid]);
}

__global__ __launch_bounds__(256) void finalize_kernel(float* __restrict__ out,
                                                       const float* __restrict__ counts,
                                                       const float* __restrict__ coords,
                                                       const float* __restrict__ posW,
                                                       const float* __restrict__ posb) {
    const int idx = blockIdx.x * 256 + threadIdx.x;
    if (idx >= BATCH * NSEG * CHAN) return;
    const int c = idx % CHAN;
    const int s = (idx / CHAN) % NSEG;
    const int b = idx / (CHAN * NSEG);
    const float cntf = fmaxf(counts[b * NSEG + s], 1.0f);
    const float x = coords[(b * NSEG + s) * 2 + 0] * (1.0f / 224.0f);
    const float y = coords[(b * NSEG + s) * 2 + 1] * (1.0f / 224.0f);
    const float pos = x * posW[c] + y * posW[CHAN + c] + posb[c];
    out[idx] = out[idx] / cntf + pos;
}

extern "C" void kernel_launch(void* const* d_in, const int* in_sizes, int n_in,
                              void* d_out, int out_size, void* d_ws, size_t ws_size,
                              hipStream_t stream) {
    const float* feat   = (const float*)d_in[1];
    const int*   seg    = (const int*)d_in[2];
    const float* coords = (const float*)d_in[3];
    const float* posW   = (const float*)d_in[4];
    const float* posb   = (const float*)d_in[5];
    float* out    = (float*)d_out;
    float* counts = (float*)d_ws;   // BATCH*NSEG floats

    hipMemsetAsync(out, 0, (size_t)BATCH * NSEG * CHAN * sizeof(float), stream);
    hipMemsetAsync(counts, 0, (size_t)BATCH * NSEG * sizeof(float), stream);

    accum_scatter<<<dim3(16, 2, BATCH), 1024, 0, stream>>>(feat, seg, out, counts);

    const int n = BATCH * NSEG * CHAN;
    finalize_kernel<<<dim3((n + 255) / 256), 256, 0, stream>>>(out, counts, coords, posW, posb);
}

// Round 2
// 887.540 us; speedup vs baseline: 1.5810x; 1.5810x over previous
//
#include <hip/hip_runtime.h>

// Shapes fixed by setup_inputs()
#define BATCH 16
#define CHAN 192
#define HW 50176            // 224*224
#define NSEG 196
#define NSEGT 13            // ceil(196/16) seg-tiles (208 padded; rows >=196 all-zero)
#define PIXSPLIT 16
#define PPB (HW / PIXSPLIT) // 3136 pixels per block
#define KSTEPS (PPB / 32)   // 98 k-steps of 32 pixels

typedef __attribute__((ext_vector_type(8))) short short8; // 8 bf16 = one MFMA A/B frag
typedef __attribute__((ext_vector_type(4))) float f32x4;
typedef __attribute__((ext_vector_type(4))) int   i32x4;

__device__ __forceinline__ short bfc(float x) {            // f32 -> bf16, round-half-up
    unsigned u = __float_as_uint(x);
    return (short)((u + 0x8000u) >> 16);
}

// One-hot MFMA segment-sum, register-built A (no LDS reads, no barriers in hot loop).
// Grid (PIXSPLIT, 2, BATCH) = 512 blocks, block 384 (6 waves) -> 2 blocks/CU, 12 waves/CU.
// Wave w owns 16 channels cbase=(by*6+w)*16; builds its own one-hot A-frags in VGPRs:
// af[j] = (seg[k]-m == 16t) -- 1 v_cmp + 1 v_cndmask per element, replaces 13 ds_read_b128/k-step.
// Counts fused (wave 0 of chan-group 0, LDS histogram). Flush: plain stores to partial
// buffer (reduced by reduce_fin) if ws is big enough, else atomicAdd fallback.
__global__ __launch_bounds__(384, 3) void accum_mfma(
        const float* __restrict__ feat,
        const int*   __restrict__ seg,
        float*       __restrict__ dst,     // partial buffer (partial=1) or out (partial=0)
        int*         __restrict__ counts,
        const int partial) {
    __shared__ int scnt[NSEG];             // only wave 0 of blockIdx.y==0 touches

    const int tid  = threadIdx.x;
    const int wave = tid >> 6;
    const int lane = tid & 63;
    const int quad = lane >> 4;
    const int m    = lane & 15;

    const int b      = blockIdx.z;
    const int cbase  = (blockIdx.y * 6 + wave) * 16;
    const int pstart = blockIdx.x * PPB;

    const bool docount = (blockIdx.y == 0) && (wave == 0);
    if (docount) {
        for (int i = lane; i < NSEG; i += 64) scnt[i] = 0;  // same wave inits & uses: no barrier
    }

    const int*   sptr = seg  + (size_t)b * HW + pstart;
    const float* fptr = feat + ((size_t)b * CHAN + cbase + m) * HW + pstart;

    f32x4 acc[NSEGT];
#pragma unroll
    for (int t = 0; t < NSEGT; ++t) acc[t] = (f32x4)0.0f;

    // software pipeline depth 1
    i32x4 s0 = *(const i32x4*)(sptr + quad * 8);
    i32x4 s1 = *(const i32x4*)(sptr + quad * 8 + 4);
    f32x4 f0 = *(const f32x4*)(fptr + quad * 8);
    f32x4 f1 = *(const f32x4*)(fptr + quad * 8 + 4);

    for (int kk = 0; kk < KSTEPS; ++kk) {
        const int sv[8] = {s0.x, s0.y, s0.z, s0.w, s1.x, s1.y, s1.z, s1.w};

        // B frag: B[k=quad*8+j][n=m] = feat[cbase+n][pbase+k] (bf16)
        short8 bf;
        bf[0] = bfc(f0.x); bf[1] = bfc(f0.y); bf[2] = bfc(f0.z); bf[3] = bfc(f0.w);
        bf[4] = bfc(f1.x); bf[5] = bfc(f1.y); bf[6] = bfc(f1.z); bf[7] = bfc(f1.w);

        // fused counts: one lane per quad counts its 8 (quad-uniform) seg values
        if (docount && m == 0) {
#pragma unroll
            for (int j = 0; j < 8; ++j) atomicAdd(&scnt[sv[j]], 1);
        }

        // prefetch next k-step (last iter reloads current: harmless)
        const int pn = (kk + 1 < KSTEPS ? kk + 1 : kk) * 32;
        i32x4 s0n = *(const i32x4*)(sptr + pn + quad * 8);
        i32x4 s1n = *(const i32x4*)(sptr + pn + quad * 8 + 4);
        f32x4 f0n = *(const f32x4*)(fptr + pn + quad * 8);
        f32x4 f1n = *(const f32x4*)(fptr + pn + quad * 8 + 4);

        // d[j] = seg - m; one-hot for tile t iff d == 16t (compare vs hoisted constants)
        int d[8];
#pragma unroll
        for (int j = 0; j < 8; ++j) d[j] = sv[j] - m;

#pragma unroll
        for (int t = 0; t < NSEGT; ++t) {
            short8 af;
#pragma unroll
            for (int j = 0; j < 8; ++j)
                af[j] = (d[j] == t * 16) ? (short)0x3F80 : (short)0;
            acc[t] = __builtin_amdgcn_mfma_f32_16x16x32_bf16(af, bf, acc[t], 0, 0, 0);
        }

        s0 = s0n; s1 = s1n; f0 = f0n; f1 = f1n;
    }

    // C/D layout: col(c) = lane&15, row(s_local) = quad*4 + reg
    if (partial) {
        float* obase = dst + (((size_t)blockIdx.x * BATCH + b) * NSEG) * CHAN + cbase + m;
#pragma unroll
        for (int t = 0; t < NSEGT; ++t) {
#pragma unroll
            for (int r = 0; r < 4; ++r) {
                const int s = t * 16 + quad * 4 + r;
                if (s < NSEG) obase[(size_t)s * CHAN] = acc[t][r];
            }
        }
    } else {
        float* obase = dst + ((size_t)b * NSEG) * CHAN + cbase + m;
#pragma unroll
        for (int t = 0; t < NSEGT; ++t) {
#pragma unroll
            for (int r = 0; r < 4; ++r) {
                const int s = t * 16 + quad * 4 + r;
                if (s < NSEG) atomicAdd(obase + (size_t)s * CHAN, acc[t][r]);
            }
        }
    }
    if (docount) {
        for (int i = lane; i < NSEG; i += 64) atomicAdd(&counts[b * NSEG + i], scnt[i]);
    }
}

// Fused partial-reduce + finalize: out = sum_p(part)/max(cnt,1) + pos
__global__ __launch_bounds__(256) void reduce_fin(const float* __restrict__ part,
                                                  const int* __restrict__ counts,
                                                  const float* __restrict__ coords,
                                                  const float* __restrict__ posW,
                                                  const float* __restrict__ posb,
                                                  float* __restrict__ out) {
    const int idx = blockIdx.x * 256 + threadIdx.x;
    if (idx >= BATCH * NSEG * CHAN) return;
    const int c = idx % CHAN;
    const int s = (idx / CHAN) % NSEG;
    const int b = idx / (CHAN * NSEG);
    float sum = 0.0f;
#pragma unroll
    for (int p = 0; p < PIXSPLIT; ++p)
        sum += part[(size_t)p * (BATCH * NSEG * CHAN) + idx];
    const float cntf = (float)max(counts[b * NSEG + s], 1);
    const float x = coords[(b * NSEG + s) * 2 + 0] * (1.0f / 224.0f);
    const float y = coords[(b * NSEG + s) * 2 + 1] * (1.0f / 224.0f);
    const float pos = x * posW[c] + y * posW[CHAN + c] + posb[c];
    out[idx] = sum / cntf + pos;
}

// Fallback finalize for the atomic-flush path
__global__ __launch_bounds__(256) void finalize_kernel(float* __restrict__ out,
                                                       const int* __restrict__ counts,
                                                       const float* __restrict__ coords,
                                                       const float* __restrict__ posW,
                                                       const float* __restrict__ posb) {
    const int idx = blockIdx.x * 256 + threadIdx.x;
    if (idx >= BATCH * NSEG * CHAN) return;
    const int c = idx % CHAN;
    const int s = (idx / CHAN) % NSEG;
    const int b = idx / (CHAN * NSEG);
    const float cntf = (float)max(counts[b * NSEG + s], 1);
    const float x = coords[(b * NSEG + s) * 2 + 0] * (1.0f / 224.0f);
    const float y = coords[(b * NSEG + s) * 2 + 1] * (1.0f / 224.0f);
    const float pos = x * posW[c] + y * posW[CHAN + c] + posb[c];
    out[idx] = out[idx] / cntf + pos;
}

extern "C" void kernel_launch(void* const* d_in, const int* in_sizes, int n_in,
                              void* d_out, int out_size, void* d_ws, size_t ws_size,
                              hipStream_t stream) {
    const float* feat   = (const float*)d_in[1];
    const int*   seg    = (const int*)d_in[2];
    const float* coords = (const float*)d_in[3];
    const float* posW   = (const float*)d_in[4];
    const float* posb   = (const float*)d_in[5];
    float* out    = (float*)d_out;
    int*   counts = (int*)d_ws;   // BATCH*NSEG ints at ws[0]

    const size_t part_off   = 12800;  // 256B-aligned, past 16*196*4 = 12544 count bytes
    const size_t part_bytes = (size_t)PIXSPLIT * BATCH * NSEG * CHAN * sizeof(float); // 38.5 MB
    float* part = (float*)((char*)d_ws + part_off);
    const bool use_part = ws_size >= part_off + part_bytes;

    hipMemsetAsync(counts, 0, (size_t)BATCH * NSEG * sizeof(int), stream);
    if (!use_part)
        hipMemsetAsync(out, 0, (size_t)BATCH * NSEG * CHAN * sizeof(float), stream);

    accum_mfma<<<dim3(PIXSPLIT, 2, BATCH), 384, 0, stream>>>(
        feat, seg, use_part ? part : out, counts, use_part ? 1 : 0);

    const int n = BATCH * NSEG * CHAN;
    if (use_part)
        reduce_fin<<<dim3((n + 255) / 256), 256, 0, stream>>>(part, counts, coords, posW, posb, out);
    else
        finalize_kernel<<<dim3((n + 255) / 256), 256, 0, stream>>>(out, counts, coords, posW, posb);
}